// Round 2
// baseline (2655.576 us; speedup 1.0000x reference)
//
#include <hip/hip_runtime.h>

#define NLAYERS 3
#define BB 32
#define LL 336
#define NN 321
#define EE 4
#define DHID 512
#define PP 96
#define STOT (BB*NN*LL)   // 3451392

__device__ __forceinline__ float softplus_f(float x) {
    return fmaxf(x, 0.0f) + log1pf(expf(-fabsf(x)));
}

__device__ __forceinline__ float gelu_f(float x) {
    // jax.nn.gelu default: approximate=True (tanh form)
    float t = tanhf(0.7978845608028654f * (x + 0.044715f * x * x * x));
    return 0.5f * x * (1.0f + t);
}

// ---------------- RevIN (per (b,n) over time axis), also zeros loss ----------------
__global__ __launch_bounds__(256) void revin_kernel(
    const float* __restrict__ x, float* __restrict__ T, float* __restrict__ loss)
{
    int idx = blockIdx.x * 256 + threadIdx.x;
    if (idx == 0) loss[0] = 0.0f;
    if (idx >= BB * NN) return;
    int b = idx / NN, n = idx - b * NN;
    const float* xp = x + (size_t)b * LL * NN + n;
    float s = 0.f, ss = 0.f;
    for (int l = 0; l < LL; ++l) {
        float v = xp[(size_t)l * NN];
        s += v; ss = fmaf(v, v, ss);
    }
    float mu  = s * (1.0f / LL);
    float var = ss * (1.0f / LL) - mu * mu;   // ddof=0 (jnp.var default)
    float inv = 1.0f / sqrtf(var + 1e-5f);
    float* tp = T + (size_t)idx * LL;
    for (int l = 0; l < LL; ++l)
        tp[l] = (xp[(size_t)l * NN] - mu) * inv;
}

// ---------------- gate features g[b,l] = mean_n T[b,n,l] ----------------
__global__ __launch_bounds__(384) void gmean_kernel(
    const float* __restrict__ T, float* __restrict__ G)
{
    int b = blockIdx.x;
    int l = threadIdx.x;
    if (l >= LL) return;
    const float* tp = T + (size_t)b * NN * LL + l;
    float s = 0.f;
    for (int n = 0; n < NN; ++n) s += tp[(size_t)n * LL];
    G[b * LL + l] = s * (1.0f / NN);
}

// ---------------- noisy top-k gating + aux loss (single block, 128 thr) ----------------
__global__ __launch_bounds__(128) void gating_kernel(
    const float* __restrict__ G, const float* __restrict__ wg,
    const float* __restrict__ wn, const float* __restrict__ noise,
    float* __restrict__ gates_out, float* __restrict__ loss)
{
    __shared__ float s_clean[BB][EE], s_nstd[BB][EE], s_noisy[BB][EE], s_gates[BB][EE];
    __shared__ float s_thr_in[BB], s_thr_out[BB];
    __shared__ float s_imp[EE], s_load[EE];
    int tid = threadIdx.x;            // 128 = BB*EE
    int b = tid >> 2, e = tid & 3;
    float c = 0.f, nr = 0.f;
    const float* gp = G + b * LL;
    for (int l = 0; l < LL; ++l) {
        float gv = gp[l];
        c  = fmaf(gv, wg[l * EE + e], c);
        nr = fmaf(gv, wn[l * EE + e], nr);
    }
    float nstd  = softplus_f(nr) + 1e-2f;
    float noisy = fmaf(noise[b * EE + e], nstd, c);
    s_clean[b][e] = c; s_nstd[b][e] = nstd; s_noisy[b][e] = noisy;
    __syncthreads();
    if (e == 0) {
        float v[4];
        #pragma unroll
        for (int i = 0; i < 4; ++i) v[i] = s_noisy[b][i];
        int i0 = 0;
        for (int i = 1; i < 4; ++i) if (v[i] > v[i0]) i0 = i;
        int i1 = -1;
        for (int i = 0; i < 4; ++i) { if (i == i0) continue; if (i1 < 0 || v[i] > v[i1]) i1 = i; }
        float m3 = -1e30f;
        for (int i = 0; i < 4; ++i) { if (i == i0 || i == i1) continue; if (v[i] > m3) m3 = v[i]; }
        float e1  = expf(v[i1] - v[i0]);
        float invd = 1.0f / (1.0f + e1);
        #pragma unroll
        for (int i = 0; i < 4; ++i) s_gates[b][i] = 0.f;
        s_gates[b][i0] = invd;
        s_gates[b][i1] = e1 * invd;
        s_thr_in[b]  = m3;       // (k+1)-th value
        s_thr_out[b] = v[i1];    // k-th value
    }
    __syncthreads();
    gates_out[b * EE + e] = s_gates[b][e];
    if (tid < EE) {
        int ee = tid;
        float imp = 0.f, ld = 0.f;
        for (int bb = 0; bb < BB; ++bb) {
            imp += s_gates[bb][ee];
            float thr = (s_noisy[bb][ee] > s_thr_in[bb]) ? s_thr_in[bb] : s_thr_out[bb];
            float z = (s_clean[bb][ee] - thr) / s_nstd[bb][ee];
            ld += 0.5f * (1.0f + erff(z * 0.7071067811865476f));
        }
        s_imp[ee] = imp; s_load[ee] = ld;
    }
    __syncthreads();
    if (tid == 0) {
        float aux = 0.f;
        {
            float m = (s_imp[0] + s_imp[1] + s_imp[2] + s_imp[3]) * 0.25f;
            float var = 0.f;
            for (int i = 0; i < 4; ++i) { float d = s_imp[i] - m; var += d * d; }
            var *= (1.0f / 3.0f);                      // ddof=1
            aux += var / (m * m + 1e-10f);
        }
        {
            float m = (s_load[0] + s_load[1] + s_load[2] + s_load[3]) * 0.25f;
            float var = 0.f;
            for (int i = 0; i < 4; ++i) { float d = s_load[i] - m; var += d * d; }
            var *= (1.0f / 3.0f);
            aux += var / (m * m + 1e-10f);
        }
        loss[0] += 0.01f * aux;
    }
}

// ---------------- residual init: pong = ping ----------------
__global__ __launch_bounds__(256) void copy_kernel(
    float4* __restrict__ dst, const float4* __restrict__ src)
{
    int i = blockIdx.x * 256 + threadIdx.x;
    if (i < STOT / 4) dst[i] = src[i];
}

// ---------------- FC1: H = gelu(T @ W1 + b1), per expert, gate-skipped ----------------
__global__ __launch_bounds__(256) void fc1_kernel(
    const float* __restrict__ T, const float* __restrict__ W1,
    const float* __restrict__ b1, float* __restrict__ H,
    const float* __restrict__ gates, int e)
{
    int b = blockIdx.z;
    if (gates[b * EE + e] == 0.0f) return;
    __shared__ float As[16][68];   // padded: stride 68 keeps 16B align, <=2-way banks
    __shared__ float Bs[16][68];
    int tid = threadIdx.x;
    int tm = tid & 15, tn = tid >> 4;
    int m0 = blockIdx.y * 64;
    int n0 = blockIdx.x * 64;
    int rowbase = b * NN;
    float acc[4][4] = {};
    for (int kk = 0; kk < LL; kk += 16) {
        #pragma unroll
        for (int i = 0; i < 4; ++i) {
            int lin = tid + i * 256;
            int r = lin >> 4, kc = lin & 15;
            int m = m0 + r;
            As[kc][r] = (m < NN) ? T[(size_t)(rowbase + m) * LL + kk + kc] : 0.0f;
        }
        #pragma unroll
        for (int i = 0; i < 4; ++i) {
            int lin = tid + i * 256;
            int kc = lin >> 6, c = lin & 63;
            Bs[kc][c] = W1[(size_t)(kk + kc) * DHID + n0 + c];
        }
        __syncthreads();
        #pragma unroll
        for (int kc = 0; kc < 16; ++kc) {
            float a[4], q[4];
            #pragma unroll
            for (int i = 0; i < 4; ++i) a[i] = As[kc][tm * 4 + i];
            #pragma unroll
            for (int j = 0; j < 4; ++j) q[j] = Bs[kc][tn * 4 + j];
            #pragma unroll
            for (int i = 0; i < 4; ++i)
                #pragma unroll
                for (int j = 0; j < 4; ++j)
                    acc[i][j] = fmaf(a[i], q[j], acc[i][j]);
        }
        __syncthreads();
    }
    int c0 = n0 + tn * 4;
    float bias[4];
    #pragma unroll
    for (int j = 0; j < 4; ++j) bias[j] = b1[c0 + j];
    #pragma unroll
    for (int i = 0; i < 4; ++i) {
        int m = m0 + tm * 4 + i;
        if (m >= NN) continue;
        float4 v;
        v.x = gelu_f(acc[i][0] + bias[0]);
        v.y = gelu_f(acc[i][1] + bias[1]);
        v.z = gelu_f(acc[i][2] + bias[2]);
        v.w = gelu_f(acc[i][3] + bias[3]);
        *(float4*)&H[(size_t)(rowbase + m) * DHID + c0] = v;
    }
}

// ---------------- FC2: Tout += gate * (H @ W2 + b2), per expert, gate-skipped ----------------
__global__ __launch_bounds__(256) void fc2_kernel(
    const float* __restrict__ H, const float* __restrict__ W2,
    const float* __restrict__ b2, float* __restrict__ Tout,
    const float* __restrict__ gates, int e)
{
    int b = blockIdx.z;
    float g = gates[b * EE + e];
    if (g == 0.0f) return;
    __shared__ float As[16][68];
    __shared__ float Bs[16][68];
    int tid = threadIdx.x;
    int tm = tid & 15, tn = tid >> 4;
    int m0 = blockIdx.y * 64;
    int n0 = blockIdx.x * 64;
    int rowbase = b * NN;
    float acc[4][4] = {};
    for (int kk = 0; kk < DHID; kk += 16) {
        #pragma unroll
        for (int i = 0; i < 4; ++i) {
            int lin = tid + i * 256;
            int r = lin >> 4, kc = lin & 15;
            int m = m0 + r;
            As[kc][r] = (m < NN) ? H[(size_t)(rowbase + m) * DHID + kk + kc] : 0.0f;
        }
        #pragma unroll
        for (int i = 0; i < 4; ++i) {
            int lin = tid + i * 256;
            int kc = lin >> 6, c = lin & 63;
            int cc = n0 + c;
            Bs[kc][c] = (cc < LL) ? W2[(size_t)(kk + kc) * LL + cc] : 0.0f;
        }
        __syncthreads();
        #pragma unroll
        for (int kc = 0; kc < 16; ++kc) {
            float a[4], q[4];
            #pragma unroll
            for (int i = 0; i < 4; ++i) a[i] = As[kc][tm * 4 + i];
            #pragma unroll
            for (int j = 0; j < 4; ++j) q[j] = Bs[kc][tn * 4 + j];
            #pragma unroll
            for (int i = 0; i < 4; ++i)
                #pragma unroll
                for (int j = 0; j < 4; ++j)
                    acc[i][j] = fmaf(a[i], q[j], acc[i][j]);
        }
        __syncthreads();
    }
    int c0 = n0 + tn * 4;
    if (c0 < LL) {   // LL % 4 == 0, so whole float4 is in/out of bounds together
        float bias[4];
        #pragma unroll
        for (int j = 0; j < 4; ++j) bias[j] = b2[c0 + j];
        #pragma unroll
        for (int i = 0; i < 4; ++i) {
            int m = m0 + tm * 4 + i;
            if (m >= NN) continue;
            float4* p = (float4*)&Tout[(size_t)(rowbase + m) * LL + c0];
            float4 v = *p;
            v.x += g * (acc[i][0] + bias[0]);
            v.y += g * (acc[i][1] + bias[1]);
            v.z += g * (acc[i][2] + bias[2]);
            v.w += g * (acc[i][3] + bias[3]);
            *p = v;
        }
    }
}

// ---------------- fused projection head: tanh(T@p1w^T+b) @ p2w^T + b -> mean/std ----------------
__global__ __launch_bounds__(256) void proj_kernel(
    const float* __restrict__ T,
    const float* __restrict__ p1w, const float* __restrict__ p1b,
    const float* __restrict__ p2w, const float* __restrict__ p2b,
    float* __restrict__ out)
{
    __shared__ float Al[32][340];   // 32 rows x 336, stride 340 breaks bank strides
    __shared__ float Hp[32][100];   // 32 x 96, stride 100
    int tid = threadIdx.x;
    int row0 = blockIdx.x * 32;
    for (int i = 0; i < 42; ++i) {
        int lin = tid + i * 256;          // < 10752 = 32*336
        int r = lin / LL, c = lin - r * LL;
        Al[r][c] = T[(size_t)(row0 + r) * LL + c];
    }
    __syncthreads();
    {
        int r = tid >> 3;                 // 0..31
        int pbase = (tid & 7) * 12;       // 12 p-cols per thread
        float acc[12];
        #pragma unroll
        for (int i = 0; i < 12; ++i) acc[i] = p1b[pbase + i];
        for (int k = 0; k < LL; ++k) {
            float a = Al[r][k];
            #pragma unroll
            for (int i = 0; i < 12; ++i)
                acc[i] = fmaf(a, p1w[(size_t)(pbase + i) * LL + k], acc[i]);
        }
        #pragma unroll
        for (int i = 0; i < 12; ++i) Hp[r][pbase + i] = tanhf(acc[i]);
    }
    __syncthreads();
    {
        int r = tid >> 3;
        int cbase = (tid & 7) * 24;       // 24 of 192 cols per thread
        float acc[24];
        #pragma unroll
        for (int i = 0; i < 24; ++i) acc[i] = p2b[cbase + i];
        for (int k = 0; k < PP; ++k) {
            float h = Hp[r][k];
            #pragma unroll
            for (int i = 0; i < 24; ++i)
                acc[i] = fmaf(h, p2w[(size_t)(cbase + i) * PP + k], acc[i]);
        }
        int grow = row0 + r;
        int bq = grow / NN, n = grow - bq * NN;
        #pragma unroll
        for (int i = 0; i < 24; ++i) {
            int c = cbase + i;
            int p = c >> 1;
            size_t o = ((size_t)bq * PP + p) * NN + n;
            if ((c & 1) == 0)
                out[o] = acc[i];                                         // mean
            else
                out[(size_t)BB * PP * NN + 1 + o] = softplus_f(acc[i]) + 1e-6f;  // std
        }
    }
}

__global__ void loss_write_kernel(const float* __restrict__ loss, float* __restrict__ out)
{
    if (threadIdx.x == 0) out[(size_t)BB * PP * NN] = loss[0];
}

extern "C" void kernel_launch(void* const* d_in, const int* in_sizes, int n_in,
                              void* d_out, int out_size, void* d_ws, size_t ws_size,
                              hipStream_t stream)
{
    const float* x     = (const float*)d_in[0];
    const float* noise = (const float*)d_in[1];
    const float* wg    = (const float*)d_in[2];
    const float* wn    = (const float*)d_in[3];
    const float* W1    = (const float*)d_in[4];
    const float* b1    = (const float*)d_in[5];
    const float* W2    = (const float*)d_in[6];
    const float* b2    = (const float*)d_in[7];
    const float* p1w   = (const float*)d_in[8];
    const float* p1b   = (const float*)d_in[9];
    const float* p2w   = (const float*)d_in[10];
    const float* p2b   = (const float*)d_in[11];
    float* out = (float*)d_out;

    float* ws    = (float*)d_ws;
    float* T0    = ws;
    float* T1    = T0 + STOT;
    float* G     = T1 + STOT;
    float* GATES = G + BB * LL;
    float* LOSS  = GATES + BB * EE;
    float* H     = LOSS + 8;          // [B*N, DHID] fp32, per-expert reuse

    revin_kernel<<<(BB * NN + 255) / 256, 256, 0, stream>>>(x, T0, LOSS);

    float* ping = T0;
    float* pong = T1;
    for (int l = 0; l < NLAYERS; ++l) {
        gmean_kernel<<<BB, 384, 0, stream>>>(ping, G);
        gating_kernel<<<1, 128, 0, stream>>>(G, wg + l * LL * EE, wn + l * LL * EE,
                                             noise + l * BB * EE, GATES, LOSS);
        copy_kernel<<<(STOT / 4 + 255) / 256, 256, 0, stream>>>((float4*)pong, (const float4*)ping);
        for (int e = 0; e < EE; ++e) {
            const float* W1e = W1 + (size_t)(l * EE + e) * LL * DHID;
            const float* b1e = b1 + (size_t)(l * EE + e) * DHID;
            const float* W2e = W2 + (size_t)(l * EE + e) * DHID * LL;
            const float* b2e = b2 + (size_t)(l * EE + e) * LL;
            fc1_kernel<<<dim3(DHID / 64, (NN + 63) / 64, BB), 256, 0, stream>>>(
                ping, W1e, b1e, H, GATES, e);
            fc2_kernel<<<dim3((LL + 63) / 64, (NN + 63) / 64, BB), 256, 0, stream>>>(
                H, W2e, b2e, pong, GATES, e);
        }
        float* t = ping; ping = pong; pong = t;
    }
    proj_kernel<<<(BB * NN) / 32, 256, 0, stream>>>(ping, p1w, p1b, p2w, p2b, out);
    loss_write_kernel<<<1, 64, 0, stream>>>(LOSS, out);
}

// Round 3
// 698.426 us; speedup vs baseline: 3.8022x; 3.8022x over previous
//
#include <hip/hip_runtime.h>
#include <hip/hip_bf16.h>

#define NLAYERS 3
#define BB 32
#define LL 336
#define NN 321
#define EE 4
#define DHID 512
#define PP 96
#define STOT (BB*NN*LL)        // 3451392
#define MROWS (BB*NN)          // 10272
#define NW1 (NLAYERS*EE*LL*DHID) // 2064384
#define BPN ((size_t)BB*PP*NN) // 986112

typedef __attribute__((ext_vector_type(8))) short short8;
typedef __attribute__((ext_vector_type(4))) float float4v;

union S8 { short8 v; uint4 u; short s[8]; };
union BF { __hip_bfloat16 h; short s; };

__device__ __forceinline__ short f2b(float f) { BF u; u.h = __float2bfloat16(f); return u.s; }

__device__ __forceinline__ float fast_tanh(float y) {
    float e = __expf(2.0f * y);
    return 1.0f - 2.0f / (e + 1.0f);   // exact limits at +-inf
}
__device__ __forceinline__ float gelu_f(float x) {
    return 0.5f * x * (1.0f + fast_tanh(0.7978845608028654f * (x + 0.044715f * x * x * x)));
}
__device__ __forceinline__ float softplus_f(float x) {
    return fmaxf(x, 0.0f) + log1pf(expf(-fabsf(x)));
}

// ---------------- RevIN (per (b,n) over time axis), also zeros loss ----------------
__global__ __launch_bounds__(256) void revin_kernel(
    const float* __restrict__ x, float* __restrict__ T, float* __restrict__ loss)
{
    int idx = blockIdx.x * 256 + threadIdx.x;
    if (idx == 0) loss[0] = 0.0f;
    if (idx >= MROWS) return;
    int b = idx / NN, n = idx - b * NN;
    const float* xp = x + (size_t)b * LL * NN + n;
    float s = 0.f, ss = 0.f;
    for (int l = 0; l < LL; ++l) {
        float v = xp[(size_t)l * NN];
        s += v; ss = fmaf(v, v, ss);
    }
    float mu  = s * (1.0f / LL);
    float var = ss * (1.0f / LL) - mu * mu;   // ddof=0
    float inv = 1.0f / sqrtf(var + 1e-5f);
    float* tp = T + (size_t)idx * LL;
    for (int l = 0; l < LL; ++l)
        tp[l] = (xp[(size_t)l * NN] - mu) * inv;
}

// ---------------- weight convert + transpose to bf16 [d][k] layouts ----------------
__global__ __launch_bounds__(256) void wcvt_kernel(
    const float* __restrict__ W1, const float* __restrict__ W2,
    const float* __restrict__ p1w, const float* __restrict__ p2w,
    short* __restrict__ W1t, short* __restrict__ W2t,
    short* __restrict__ p1wb, short* __restrict__ p2wb)
{
    int i = blockIdx.x * 256 + threadIdx.x;
    if (i < NW1) {                       // W1t[le][d=512][k=336] <- W1[le][k][d]
        int le = i / (DHID * LL);
        int r  = i - le * (DHID * LL);
        int d  = r / LL, k = r - d * LL;
        W1t[i] = f2b(W1[((size_t)le * LL + k) * DHID + d]);
    } else if (i < 2 * NW1) {            // W2t[le][d=336][k=512] <- W2[le][k][d]
        int j  = i - NW1;
        int le = j / (DHID * LL);
        int r  = j - le * (DHID * LL);
        int d  = r >> 9, k = r & 511;
        W2t[j] = f2b(W2[((size_t)le * DHID + k) * LL + d]);
    } else if (i < 2 * NW1 + PP * LL) {  // p1w already [n][k]
        int j = i - 2 * NW1;
        p1wb[j] = f2b(p1w[j]);
    } else if (i < 2 * NW1 + PP * LL + 2 * PP * PP) {
        int j = i - 2 * NW1 - PP * LL;   // p2w already [n][k]
        p2wb[j] = f2b(p2w[j]);
    }
}

// ---------------- gate features g[b,l] = mean_n T[b,n,l] ----------------
__global__ __launch_bounds__(384) void gmean_kernel(
    const float* __restrict__ T, float* __restrict__ G)
{
    int b = blockIdx.x;
    int l = threadIdx.x;
    if (l >= LL) return;
    const float* tp = T + (size_t)b * NN * LL + l;
    float s = 0.f;
    for (int n = 0; n < NN; ++n) s += tp[(size_t)n * LL];
    G[b * LL + l] = s * (1.0f / NN);
}

// ---------------- noisy top-k gating + aux loss; emits compact top2 lists ----------------
__global__ __launch_bounds__(128) void gating_kernel(
    const float* __restrict__ G, const float* __restrict__ wg,
    const float* __restrict__ wn, const float* __restrict__ noise,
    int* __restrict__ IDX, float* __restrict__ GV, float* __restrict__ loss)
{
    __shared__ float s_clean[BB][EE], s_nstd[BB][EE], s_noisy[BB][EE], s_gates[BB][EE];
    __shared__ float s_thr_in[BB], s_thr_out[BB];
    __shared__ float s_imp[EE], s_load[EE];
    int tid = threadIdx.x;            // 128 = BB*EE
    int b = tid >> 2, e = tid & 3;
    float c = 0.f, nr = 0.f;
    const float* gp = G + b * LL;
    for (int l = 0; l < LL; ++l) {
        float gv = gp[l];
        c  = fmaf(gv, wg[l * EE + e], c);
        nr = fmaf(gv, wn[l * EE + e], nr);
    }
    float nstd  = softplus_f(nr) + 1e-2f;
    float noisy = fmaf(noise[b * EE + e], nstd, c);
    s_clean[b][e] = c; s_nstd[b][e] = nstd; s_noisy[b][e] = noisy;
    __syncthreads();
    if (e == 0) {
        float v[4];
        #pragma unroll
        for (int i = 0; i < 4; ++i) v[i] = s_noisy[b][i];
        int i0 = 0;
        for (int i = 1; i < 4; ++i) if (v[i] > v[i0]) i0 = i;
        int i1 = -1;
        for (int i = 0; i < 4; ++i) { if (i == i0) continue; if (i1 < 0 || v[i] > v[i1]) i1 = i; }
        float m3 = -1e30f;
        for (int i = 0; i < 4; ++i) { if (i == i0 || i == i1) continue; if (v[i] > m3) m3 = v[i]; }
        float e1  = expf(v[i1] - v[i0]);
        float invd = 1.0f / (1.0f + e1);
        #pragma unroll
        for (int i = 0; i < 4; ++i) s_gates[b][i] = 0.f;
        s_gates[b][i0] = invd;
        s_gates[b][i1] = e1 * invd;
        s_thr_in[b]  = m3;       // (k+1)-th value
        s_thr_out[b] = v[i1];    // k-th value
        IDX[2*b] = i0; IDX[2*b+1] = i1;
        GV[2*b] = invd; GV[2*b+1] = e1 * invd;
    }
    __syncthreads();
    if (tid < EE) {
        int ee = tid;
        float imp = 0.f, ld = 0.f;
        for (int bb2 = 0; bb2 < BB; ++bb2) {
            imp += s_gates[bb2][ee];
            float thr = (s_noisy[bb2][ee] > s_thr_in[bb2]) ? s_thr_in[bb2] : s_thr_out[bb2];
            float z = (s_clean[bb2][ee] - thr) / s_nstd[bb2][ee];
            ld += 0.5f * (1.0f + erff(z * 0.7071067811865476f));
        }
        s_imp[ee] = imp; s_load[ee] = ld;
    }
    __syncthreads();
    if (tid == 0) {
        float aux = 0.f;
        {
            float m = (s_imp[0] + s_imp[1] + s_imp[2] + s_imp[3]) * 0.25f;
            float var = 0.f;
            for (int i = 0; i < 4; ++i) { float d = s_imp[i] - m; var += d * d; }
            var *= (1.0f / 3.0f);
            aux += var / (m * m + 1e-10f);
        }
        {
            float m = (s_load[0] + s_load[1] + s_load[2] + s_load[3]) * 0.25f;
            float var = 0.f;
            for (int i = 0; i < 4; ++i) { float d = s_load[i] - m; var += d * d; }
            var *= (1.0f / 3.0f);
            aux += var / (m * m + 1e-10f);
        }
        loss[0] += 0.01f * aux;
    }
}

// ---------------- FC1 (MFMA): Hs[z] = gate * gelu(T[b] @ W1[e] + b1[e]) ----------------
// grid (4, 6, 64): x = d-tile(128), y = n-tile(64), z = b*2+slot
__global__ __launch_bounds__(256) void fc1_mfma(
    const float* __restrict__ T, const short* __restrict__ W1t_l,
    const float* __restrict__ b1_l, const int* __restrict__ IDX,
    const float* __restrict__ GV, short* __restrict__ Hs)
{
    int z = blockIdx.z;
    int b = z >> 1;
    int e = IDX[z];
    float g = GV[z];
    __shared__ short Al[64][40];    // [m][k] rows padded to 40 (80B)
    __shared__ short Bl[128][40];   // [d][k]
    const float* Tb = T + (size_t)b * NN * LL;
    const short* Wb = W1t_l + (size_t)e * DHID * LL;
    const float* bb = b1_l + (size_t)e * DHID;
    int m0 = blockIdx.y * 64, n0 = blockIdx.x * 128;
    int tid = threadIdx.x;
    int wave = tid >> 6, lane = tid & 63, quad = lane >> 4, l16 = lane & 15;
    int wn = wave * 32;
    float4v zero4 = {0.f, 0.f, 0.f, 0.f};
    float4v acc[4][2];
    #pragma unroll
    for (int i = 0; i < 4; ++i)
        #pragma unroll
        for (int j = 0; j < 2; ++j) acc[i][j] = zero4;

    int am = tid >> 2, ako = (tid & 3) * 8;
    for (int k0 = 0; k0 < LL; k0 += 32) {    // 11 chunks; tail zero-padded
        {   // A: 64x32 fp32 -> bf16
            int gm = m0 + am, gk = k0 + ako;
            S8 s;
            if (gm < NN && gk < LL) {
                const float* p = Tb + (size_t)gm * LL + gk;
                #pragma unroll
                for (int j = 0; j < 8; ++j) s.s[j] = f2b(p[j]);
            } else {
                s.u = make_uint4(0, 0, 0, 0);
            }
            *(uint4*)&Al[am][ako] = s.u;
        }
        #pragma unroll
        for (int uu = 0; uu < 2; ++uu) {     // B: 128x32 bf16 copy
            int u = tid + uu * 256;
            int n = u >> 2, ko = (u & 3) * 8;
            int gk = k0 + ko;
            uint4 val = make_uint4(0, 0, 0, 0);
            if (gk < LL) val = *(const uint4*)(Wb + (size_t)(n0 + n) * LL + gk);
            *(uint4*)&Bl[n][ko] = val;
        }
        __syncthreads();
        short8 af[4], bfv[2];
        #pragma unroll
        for (int mi = 0; mi < 4; ++mi) af[mi] = *(const short8*)&Al[mi * 16 + l16][quad * 8];
        #pragma unroll
        for (int ni = 0; ni < 2; ++ni) bfv[ni] = *(const short8*)&Bl[wn + ni * 16 + l16][quad * 8];
        #pragma unroll
        for (int mi = 0; mi < 4; ++mi)
            #pragma unroll
            for (int ni = 0; ni < 2; ++ni)
                acc[mi][ni] = __builtin_amdgcn_mfma_f32_16x16x32_bf16(af[mi], bfv[ni], acc[mi][ni], 0, 0, 0);
        __syncthreads();
    }
    float bias[2];
    #pragma unroll
    for (int ni = 0; ni < 2; ++ni) bias[ni] = bb[n0 + wn + ni * 16 + l16];
    short* Ho = Hs + (size_t)z * NN * DHID;
    #pragma unroll
    for (int mi = 0; mi < 4; ++mi) {
        #pragma unroll
        for (int r = 0; r < 4; ++r) {
            int gm = m0 + mi * 16 + quad * 4 + r;   // C/D: col=lane&15, row=quad*4+reg
            if (gm >= NN) continue;
            #pragma unroll
            for (int ni = 0; ni < 2; ++ni) {
                int gd = n0 + wn + ni * 16 + l16;
                float v = acc[mi][ni][r] + bias[ni];
                Ho[(size_t)gm * DHID + gd] = f2b(g * gelu_f(v));
            }
        }
    }
}

// ---------------- FC2 (MFMA): T[b] += Hs[b,0]@W2[e0] + Hs[b,1]@W2[e1] + g-weighted b2 ----
// grid (6, 6, 32): x = l-tile(64), y = n-tile(64), z = b. K = 2*512 slot-switched.
__global__ __launch_bounds__(256) void fc2_mfma(
    const short* __restrict__ Hs, const short* __restrict__ W2t_l,
    const float* __restrict__ b2_l, float* __restrict__ T,
    const int* __restrict__ IDX, const float* __restrict__ GV)
{
    int b = blockIdx.z;
    int e0 = IDX[2 * b], e1 = IDX[2 * b + 1];
    float g0 = GV[2 * b], g1 = GV[2 * b + 1];
    __shared__ short Al[64][40];
    __shared__ short Bl[64][40];
    int m0 = blockIdx.y * 64, n0 = blockIdx.x * 64;
    int tid = threadIdx.x;
    int wave = tid >> 6, lane = tid & 63, quad = lane >> 4, l16 = lane & 15;
    int wm = (wave & 1) * 32, wn = (wave >> 1) * 32;
    float4v zero4 = {0.f, 0.f, 0.f, 0.f};
    float4v acc[2][2];
    #pragma unroll
    for (int i = 0; i < 2; ++i)
        #pragma unroll
        for (int j = 0; j < 2; ++j) acc[i][j] = zero4;

    int sm = tid >> 2, sko = (tid & 3) * 8;
    for (int kc = 0; kc < 32; ++kc) {
        int slot = kc >> 4;
        int kk = (kc & 15) * 32 + sko;
        int e = slot ? e1 : e0;
        {   // A: 64x32 from Hs (bf16)
            int gm = m0 + sm;
            uint4 val = make_uint4(0, 0, 0, 0);
            if (gm < NN) val = *(const uint4*)(Hs + ((size_t)(2 * b + slot) * NN + gm) * DHID + kk);
            *(uint4*)&Al[sm][sko] = val;
        }
        {   // B: 64x32 from W2t (bf16, [l][k])
            int gl = n0 + sm;
            uint4 val = make_uint4(0, 0, 0, 0);
            if (gl < LL) val = *(const uint4*)(W2t_l + ((size_t)e * LL + gl) * DHID + kk);
            *(uint4*)&Bl[sm][sko] = val;
        }
        __syncthreads();
        short8 af[2], bfv[2];
        #pragma unroll
        for (int mi = 0; mi < 2; ++mi) af[mi] = *(const short8*)&Al[wm + mi * 16 + l16][quad * 8];
        #pragma unroll
        for (int ni = 0; ni < 2; ++ni) bfv[ni] = *(const short8*)&Bl[wn + ni * 16 + l16][quad * 8];
        #pragma unroll
        for (int mi = 0; mi < 2; ++mi)
            #pragma unroll
            for (int ni = 0; ni < 2; ++ni)
                acc[mi][ni] = __builtin_amdgcn_mfma_f32_16x16x32_bf16(af[mi], bfv[ni], acc[mi][ni], 0, 0, 0);
        __syncthreads();
    }
    const float* b2e0 = b2_l + (size_t)e0 * LL;
    const float* b2e1 = b2_l + (size_t)e1 * LL;
    float bias[2]; int glc[2];
    #pragma unroll
    for (int ni = 0; ni < 2; ++ni) {
        int gl = n0 + wn + ni * 16 + l16;
        glc[ni] = gl;
        bias[ni] = (gl < LL) ? (g0 * b2e0[gl] + g1 * b2e1[gl]) : 0.f;
    }
    float* Tb = T + (size_t)b * NN * LL;
    #pragma unroll
    for (int mi = 0; mi < 2; ++mi) {
        #pragma unroll
        for (int r = 0; r < 4; ++r) {
            int gm = m0 + wm + mi * 16 + quad * 4 + r;
            if (gm >= NN) continue;
            #pragma unroll
            for (int ni = 0; ni < 2; ++ni) {
                if (glc[ni] < LL)
                    Tb[(size_t)gm * LL + glc[ni]] += acc[mi][ni][r] + bias[ni];
            }
        }
    }
}

// ---------------- proj1 (MFMA): Hp = tanh(T @ p1w^T + p1b), [10272][96] bf16 ----------------
__global__ __launch_bounds__(256) void proj1_mfma(
    const float* __restrict__ T, const short* __restrict__ p1wb,
    const float* __restrict__ p1b, short* __restrict__ Hp)
{
    __shared__ short Al[64][40];
    __shared__ short Bl[96][40];
    int m0 = blockIdx.x * 64;
    int tid = threadIdx.x;
    int wave = tid >> 6, lane = tid & 63, quad = lane >> 4, l16 = lane & 15;
    float4v zero4 = {0.f, 0.f, 0.f, 0.f};
    float4v acc[6];
    #pragma unroll
    for (int i = 0; i < 6; ++i) acc[i] = zero4;
    int am = tid >> 2, ako = (tid & 3) * 8;
    for (int k0 = 0; k0 < LL; k0 += 32) {
        {
            int gm = m0 + am, gk = k0 + ako;
            S8 s;
            if (gm < MROWS && gk < LL) {
                const float* p = T + (size_t)gm * LL + gk;
                #pragma unroll
                for (int j = 0; j < 8; ++j) s.s[j] = f2b(p[j]);
            } else {
                s.u = make_uint4(0, 0, 0, 0);
            }
            *(uint4*)&Al[am][ako] = s.u;
        }
        #pragma unroll
        for (int uu = 0; uu < 2; ++uu) {
            int u = tid + uu * 256;
            if (u < 384) {
                int n = u >> 2, ko = (u & 3) * 8;
                int gk = k0 + ko;
                uint4 val = make_uint4(0, 0, 0, 0);
                if (gk < LL) val = *(const uint4*)(p1wb + (size_t)n * LL + gk);
                *(uint4*)&Bl[n][ko] = val;
            }
        }
        __syncthreads();
        short8 af = *(const short8*)&Al[wave * 16 + l16][quad * 8];
        #pragma unroll
        for (int ni = 0; ni < 6; ++ni) {
            short8 bfv = *(const short8*)&Bl[ni * 16 + l16][quad * 8];
            acc[ni] = __builtin_amdgcn_mfma_f32_16x16x32_bf16(af, bfv, acc[ni], 0, 0, 0);
        }
        __syncthreads();
    }
    #pragma unroll
    for (int r = 0; r < 4; ++r) {
        int gm = m0 + wave * 16 + quad * 4 + r;
        if (gm >= MROWS) continue;
        #pragma unroll
        for (int ni = 0; ni < 6; ++ni) {
            int gp = ni * 16 + l16;
            Hp[(size_t)gm * PP + gp] = f2b(fast_tanh(acc[ni][r] + p1b[gp]));
        }
    }
}

// ---------------- proj2 (MFMA): out = Hp @ p2w^T + p2b, scattered mean/std ----------------
__global__ __launch_bounds__(256) void proj2_mfma(
    const short* __restrict__ Hp, const short* __restrict__ p2wb,
    const float* __restrict__ p2b, float* __restrict__ out)
{
    __shared__ short Al[64][40];
    __shared__ short Bl[192][40];
    int m0 = blockIdx.x * 64;
    int tid = threadIdx.x;
    int wave = tid >> 6, lane = tid & 63, quad = lane >> 4, l16 = lane & 15;
    float4v zero4 = {0.f, 0.f, 0.f, 0.f};
    float4v acc[12];
    #pragma unroll
    for (int i = 0; i < 12; ++i) acc[i] = zero4;
    int am = tid >> 2, ako = (tid & 3) * 8;
    for (int k0 = 0; k0 < PP; k0 += 32) {   // 3 chunks, exact
        {
            int gm = m0 + am;
            uint4 val = make_uint4(0, 0, 0, 0);
            if (gm < MROWS) val = *(const uint4*)(Hp + (size_t)gm * PP + k0 + ako);
            *(uint4*)&Al[am][ako] = val;
        }
        #pragma unroll
        for (int uu = 0; uu < 3; ++uu) {
            int u = tid + uu * 256;
            int n = u >> 2, ko = (u & 3) * 8;
            uint4 val = *(const uint4*)(p2wb + (size_t)n * PP + k0 + ko);
            *(uint4*)&Bl[n][ko] = val;
        }
        __syncthreads();
        short8 af = *(const short8*)&Al[wave * 16 + l16][quad * 8];
        #pragma unroll
        for (int ni = 0; ni < 12; ++ni) {
            short8 bfv = *(const short8*)&Bl[ni * 16 + l16][quad * 8];
            acc[ni] = __builtin_amdgcn_mfma_f32_16x16x32_bf16(af, bfv, acc[ni], 0, 0, 0);
        }
        __syncthreads();
    }
    #pragma unroll
    for (int r = 0; r < 4; ++r) {
        int gm = m0 + wave * 16 + quad * 4 + r;
        if (gm >= MROWS) continue;
        int bq = gm / NN, node = gm - bq * NN;
        #pragma unroll
        for (int ni = 0; ni < 12; ++ni) {
            int c = ni * 16 + l16;
            float v = acc[ni][r] + p2b[c];
            int p = c >> 1;
            size_t o = ((size_t)bq * PP + p) * NN + node;
            if ((c & 1) == 0) out[o] = v;
            else out[BPN + 1 + o] = softplus_f(v) + 1e-6f;
        }
    }
}

__global__ void loss_write_kernel(const float* __restrict__ loss, float* __restrict__ out)
{
    if (threadIdx.x == 0) out[BPN] = loss[0];
}

extern "C" void kernel_launch(void* const* d_in, const int* in_sizes, int n_in,
                              void* d_out, int out_size, void* d_ws, size_t ws_size,
                              hipStream_t stream)
{
    const float* x     = (const float*)d_in[0];
    const float* noise = (const float*)d_in[1];
    const float* wg    = (const float*)d_in[2];
    const float* wn    = (const float*)d_in[3];
    const float* W1    = (const float*)d_in[4];
    const float* b1    = (const float*)d_in[5];
    const float* W2    = (const float*)d_in[6];
    const float* b2    = (const float*)d_in[7];
    const float* p1w   = (const float*)d_in[8];
    const float* p1b   = (const float*)d_in[9];
    const float* p2w   = (const float*)d_in[10];
    const float* p2b   = (const float*)d_in[11];
    float* out = (float*)d_out;

    float* ws   = (float*)d_ws;
    float* T    = ws;                          // STOT fp32
    float* G    = T + STOT;                    // BB*LL
    float* LOSS = G + BB * LL;                 // 8
    float* GV   = LOSS + 8;                    // 64
    int*   IDX  = (int*)(GV + 64);             // 64
    short* W1t  = (short*)(IDX + 64);          // NW1 bf16 [le][d][k]
    short* W2t  = W1t + NW1;                   // NW1 bf16 [le][d][k]
    short* p1wb = W2t + NW1;                   // 96*336
    short* p2wb = p1wb + PP * LL;              // 192*96
    short* Hs   = p2wb + 2 * PP * PP;          // 64*321*512 bf16
    short* Hp   = Hs + (size_t)BB * 2 * NN * DHID; // 10272*96 bf16

    revin_kernel<<<(MROWS + 255) / 256, 256, 0, stream>>>(x, T, LOSS);

    int wtot = 2 * NW1 + PP * LL + 2 * PP * PP;
    wcvt_kernel<<<(wtot + 255) / 256, 256, 0, stream>>>(W1, W2, p1w, p2w, W1t, W2t, p1wb, p2wb);

    for (int l = 0; l < NLAYERS; ++l) {
        gmean_kernel<<<BB, 384, 0, stream>>>(T, G);
        gating_kernel<<<1, 128, 0, stream>>>(G, wg + (size_t)l * LL * EE, wn + (size_t)l * LL * EE,
                                             noise + (size_t)l * BB * EE, IDX, GV, LOSS);
        fc1_mfma<<<dim3(4, 6, 64), 256, 0, stream>>>(
            T, W1t + (size_t)l * EE * DHID * LL, b1 + (size_t)l * EE * DHID, IDX, GV, Hs);
        fc2_mfma<<<dim3(6, 6, 32), 256, 0, stream>>>(
            Hs, W2t + (size_t)l * EE * LL * DHID, b2 + (size_t)l * EE * LL, T, IDX, GV);
    }
    proj1_mfma<<<161, 256, 0, stream>>>(T, p1wb, p1b, Hp);
    proj2_mfma<<<161, 256, 0, stream>>>(Hp, p2wb, p2b, out);
    loss_write_kernel<<<1, 64, 0, stream>>>(LOSS, out);
}

// Round 4
// 519.734 us; speedup vs baseline: 5.1095x; 1.3438x over previous
//
#include <hip/hip_runtime.h>
#include <hip/hip_bf16.h>

#define NLAYERS 3
#define BB 32
#define LL 336
#define NN 321
#define EE 4
#define DHID 512
#define PP 96
#define STOT (BB*NN*LL)        // 3451392
#define MROWS (BB*NN)          // 10272
#define NW1 (NLAYERS*EE*LL*DHID) // 2064384
#define BPN ((size_t)BB*PP*NN) // 986112

typedef __attribute__((ext_vector_type(8))) short short8;
typedef __attribute__((ext_vector_type(4))) float float4v;

union S8 { short8 v; uint4 u; short s[8]; };
union BF { __hip_bfloat16 h; short s; };

__device__ __forceinline__ short f2b(float f) { BF u; u.h = __float2bfloat16(f); return u.s; }

__device__ __forceinline__ float fast_tanh(float y) {
    float e = __expf(2.0f * y);
    return 1.0f - 2.0f / (e + 1.0f);   // exact limits at +-inf
}
__device__ __forceinline__ float gelu_f(float x) {
    return 0.5f * x * (1.0f + fast_tanh(0.7978845608028654f * (x + 0.044715f * x * x * x)));
}
__device__ __forceinline__ float softplus_f(float x) {
    return fmaxf(x, 0.0f) + log1pf(expf(-fabsf(x)));
}

// ---------------- RevIN (per (b,n) over time axis), also zeros loss ----------------
__global__ __launch_bounds__(256) void revin_kernel(
    const float* __restrict__ x, float* __restrict__ T, float* __restrict__ loss)
{
    int idx = blockIdx.x * 256 + threadIdx.x;
    if (idx == 0) loss[0] = 0.0f;
    if (idx >= MROWS) return;
    int b = idx / NN, n = idx - b * NN;
    const float* xp = x + (size_t)b * LL * NN + n;
    float s = 0.f, ss = 0.f;
    for (int l = 0; l < LL; ++l) {
        float v = xp[(size_t)l * NN];
        s += v; ss = fmaf(v, v, ss);
    }
    float mu  = s * (1.0f / LL);
    float var = ss * (1.0f / LL) - mu * mu;   // ddof=0
    float inv = 1.0f / sqrtf(var + 1e-5f);
    float* tp = T + (size_t)idx * LL;
    for (int l = 0; l < LL; ++l)
        tp[l] = (xp[(size_t)l * NN] - mu) * inv;
}

// ---------------- weight convert + transpose to bf16 [d][k] layouts ----------------
__global__ __launch_bounds__(256) void wcvt_kernel(
    const float* __restrict__ W1, const float* __restrict__ W2,
    const float* __restrict__ p1w, const float* __restrict__ p2w,
    short* __restrict__ W1t, short* __restrict__ W2t,
    short* __restrict__ p1wb, short* __restrict__ p2wb)
{
    int i = blockIdx.x * 256 + threadIdx.x;
    if (i < NW1) {                       // W1t[le][d=512][k=336] <- W1[le][k][d]
        int le = i / (DHID * LL);
        int r  = i - le * (DHID * LL);
        int d  = r / LL, k = r - d * LL;
        W1t[i] = f2b(W1[((size_t)le * LL + k) * DHID + d]);
    } else if (i < 2 * NW1) {            // W2t[le][d=336][k=512] <- W2[le][k][d]
        int j  = i - NW1;
        int le = j / (DHID * LL);
        int r  = j - le * (DHID * LL);
        int d  = r >> 9, k = r & 511;
        W2t[j] = f2b(W2[((size_t)le * DHID + k) * LL + d]);
    } else if (i < 2 * NW1 + PP * LL) {  // p1w already [n][k]
        int j = i - 2 * NW1;
        p1wb[j] = f2b(p1w[j]);
    } else if (i < 2 * NW1 + PP * LL + 2 * PP * PP) {
        int j = i - 2 * NW1 - PP * LL;   // p2w already [n][k]
        p2wb[j] = f2b(p2w[j]);
    }
}

// ---------------- gate features: 8-way partial sums over n, then reduce ----------------
__global__ __launch_bounds__(384) void gmean_part(
    const float* __restrict__ T, float* __restrict__ G8)
{
    int b = blockIdx.x, c = blockIdx.y;
    int l = threadIdx.x;
    if (l >= LL) return;
    int n_lo = c * 41, n_hi = (NN < n_lo + 41) ? NN : (n_lo + 41);
    const float* tp = T + ((size_t)b * NN + n_lo) * LL + l;
    float s = 0.f;
    for (int n = n_lo; n < n_hi; ++n, tp += LL) s += *tp;
    G8[((size_t)c * BB + b) * LL + l] = s;
}

__global__ __launch_bounds__(384) void gmean_red(
    const float* __restrict__ G8, float* __restrict__ G)
{
    int b = blockIdx.x;
    int l = threadIdx.x;
    if (l >= LL) return;
    float s = 0.f;
    #pragma unroll
    for (int c = 0; c < 8; ++c) s += G8[((size_t)c * BB + b) * LL + l];
    G[b * LL + l] = s * (1.0f / NN);
}

// ---------------- noisy top-k gating + aux loss; emits compact top2 lists ----------------
__global__ __launch_bounds__(128) void gating_kernel(
    const float* __restrict__ G, const float* __restrict__ wg,
    const float* __restrict__ wn, const float* __restrict__ noise,
    int* __restrict__ IDX, float* __restrict__ GV, float* __restrict__ loss)
{
    __shared__ float s_clean[BB][EE], s_nstd[BB][EE], s_noisy[BB][EE], s_gates[BB][EE];
    __shared__ float s_thr_in[BB], s_thr_out[BB];
    __shared__ float s_imp[EE], s_load[EE];
    int tid = threadIdx.x;            // 128 = BB*EE
    int b = tid >> 2, e = tid & 3;
    float c = 0.f, nr = 0.f;
    const float* gp = G + b * LL;
    for (int l = 0; l < LL; ++l) {
        float gv = gp[l];
        c  = fmaf(gv, wg[l * EE + e], c);
        nr = fmaf(gv, wn[l * EE + e], nr);
    }
    float nstd  = softplus_f(nr) + 1e-2f;
    float noisy = fmaf(noise[b * EE + e], nstd, c);
    s_clean[b][e] = c; s_nstd[b][e] = nstd; s_noisy[b][e] = noisy;
    __syncthreads();
    if (e == 0) {
        float v[4];
        #pragma unroll
        for (int i = 0; i < 4; ++i) v[i] = s_noisy[b][i];
        int i0 = 0;
        for (int i = 1; i < 4; ++i) if (v[i] > v[i0]) i0 = i;
        int i1 = -1;
        for (int i = 0; i < 4; ++i) { if (i == i0) continue; if (i1 < 0 || v[i] > v[i1]) i1 = i; }
        float m3 = -1e30f;
        for (int i = 0; i < 4; ++i) { if (i == i0 || i == i1) continue; if (v[i] > m3) m3 = v[i]; }
        float e1  = expf(v[i1] - v[i0]);
        float invd = 1.0f / (1.0f + e1);
        #pragma unroll
        for (int i = 0; i < 4; ++i) s_gates[b][i] = 0.f;
        s_gates[b][i0] = invd;
        s_gates[b][i1] = e1 * invd;
        s_thr_in[b]  = m3;       // (k+1)-th value
        s_thr_out[b] = v[i1];    // k-th value
        IDX[2*b] = i0; IDX[2*b+1] = i1;
        GV[2*b] = invd; GV[2*b+1] = e1 * invd;
    }
    __syncthreads();
    if (tid < EE) {
        int ee = tid;
        float imp = 0.f, ld = 0.f;
        for (int bb2 = 0; bb2 < BB; ++bb2) {
            imp += s_gates[bb2][ee];
            float thr = (s_noisy[bb2][ee] > s_thr_in[bb2]) ? s_thr_in[bb2] : s_thr_out[bb2];
            float z = (s_clean[bb2][ee] - thr) / s_nstd[bb2][ee];
            ld += 0.5f * (1.0f + erff(z * 0.7071067811865476f));
        }
        s_imp[ee] = imp; s_load[ee] = ld;
    }
    __syncthreads();
    if (tid == 0) {
        float aux = 0.f;
        {
            float m = (s_imp[0] + s_imp[1] + s_imp[2] + s_imp[3]) * 0.25f;
            float var = 0.f;
            for (int i = 0; i < 4; ++i) { float d = s_imp[i] - m; var += d * d; }
            var *= (1.0f / 3.0f);
            aux += var / (m * m + 1e-10f);
        }
        {
            float m = (s_load[0] + s_load[1] + s_load[2] + s_load[3]) * 0.25f;
            float var = 0.f;
            for (int i = 0; i < 4; ++i) { float d = s_load[i] - m; var += d * d; }
            var *= (1.0f / 3.0f);
            aux += var / (m * m + 1e-10f);
        }
        loss[0] += 0.01f * aux;
    }
}

// ---------------- FC1 (MFMA): Hs[z] = gate * gelu(T[b] @ W1[e] + b1[e]) ----------------
// grid (4, 6, 64): x = d-tile(128), y = n-tile(64), z = b*2+slot
__global__ __launch_bounds__(256) void fc1_mfma(
    const float* __restrict__ T, const short* __restrict__ W1t_l,
    const float* __restrict__ b1_l, const int* __restrict__ IDX,
    const float* __restrict__ GV, short* __restrict__ Hs)
{
    int z = blockIdx.z;
    int b = z >> 1;
    int e = IDX[z];
    float g = GV[z];
    __shared__ short Al[64][40];    // [m][k] rows padded to 40 (80B)
    __shared__ short Bl[128][40];   // [d][k]
    const float* Tb = T + (size_t)b * NN * LL;
    const short* Wb = W1t_l + (size_t)e * DHID * LL;
    const float* bb = b1_l + (size_t)e * DHID;
    int m0 = blockIdx.y * 64, n0 = blockIdx.x * 128;
    int tid = threadIdx.x;
    int wave = tid >> 6, lane = tid & 63, quad = lane >> 4, l16 = lane & 15;
    int wn = wave * 32;
    float4v zero4 = {0.f, 0.f, 0.f, 0.f};
    float4v acc[4][2];
    #pragma unroll
    for (int i = 0; i < 4; ++i)
        #pragma unroll
        for (int j = 0; j < 2; ++j) acc[i][j] = zero4;

    int am = tid >> 2, ako = (tid & 3) * 8;
    for (int k0 = 0; k0 < LL; k0 += 32) {    // 11 chunks; tail zero-padded
        {   // A: 64x32 fp32 -> bf16
            int gm = m0 + am, gk = k0 + ako;
            S8 s;
            if (gm < NN && gk < LL) {
                const float* p = Tb + (size_t)gm * LL + gk;
                #pragma unroll
                for (int j = 0; j < 8; ++j) s.s[j] = f2b(p[j]);
            } else {
                s.u = make_uint4(0, 0, 0, 0);
            }
            *(uint4*)&Al[am][ako] = s.u;
        }
        #pragma unroll
        for (int uu = 0; uu < 2; ++uu) {     // B: 128x32 bf16 copy
            int u = tid + uu * 256;
            int n = u >> 2, ko = (u & 3) * 8;
            int gk = k0 + ko;
            uint4 val = make_uint4(0, 0, 0, 0);
            if (gk < LL) val = *(const uint4*)(Wb + (size_t)(n0 + n) * LL + gk);
            *(uint4*)&Bl[n][ko] = val;
        }
        __syncthreads();
        short8 af[4], bfv[2];
        #pragma unroll
        for (int mi = 0; mi < 4; ++mi) af[mi] = *(const short8*)&Al[mi * 16 + l16][quad * 8];
        #pragma unroll
        for (int ni = 0; ni < 2; ++ni) bfv[ni] = *(const short8*)&Bl[wn + ni * 16 + l16][quad * 8];
        #pragma unroll
        for (int mi = 0; mi < 4; ++mi)
            #pragma unroll
            for (int ni = 0; ni < 2; ++ni)
                acc[mi][ni] = __builtin_amdgcn_mfma_f32_16x16x32_bf16(af[mi], bfv[ni], acc[mi][ni], 0, 0, 0);
        __syncthreads();
    }
    float bias[2];
    #pragma unroll
    for (int ni = 0; ni < 2; ++ni) bias[ni] = bb[n0 + wn + ni * 16 + l16];
    short* Ho = Hs + (size_t)z * NN * DHID;
    #pragma unroll
    for (int mi = 0; mi < 4; ++mi) {
        #pragma unroll
        for (int r = 0; r < 4; ++r) {
            int gm = m0 + mi * 16 + quad * 4 + r;   // C/D: col=lane&15, row=quad*4+reg
            if (gm >= NN) continue;
            #pragma unroll
            for (int ni = 0; ni < 2; ++ni) {
                int gd = n0 + wn + ni * 16 + l16;
                float v = acc[mi][ni][r] + bias[ni];
                Ho[(size_t)gm * DHID + gd] = f2b(g * gelu_f(v));
            }
        }
    }
}

// ---------------- FC2 (MFMA): T[b] += Hs[b,0]@W2[e0] + Hs[b,1]@W2[e1] + g-weighted b2 ----
// grid (3, 6, 32): x = l-tile(128), y = m-tile(64), z = b. K = 2*512 slot-switched.
__global__ __launch_bounds__(256) void fc2_mfma(
    const short* __restrict__ Hs, const short* __restrict__ W2t_l,
    const float* __restrict__ b2_l, float* __restrict__ T,
    const int* __restrict__ IDX, const float* __restrict__ GV)
{
    int b = blockIdx.z;
    int e0 = IDX[2 * b], e1 = IDX[2 * b + 1];
    float g0 = GV[2 * b], g1 = GV[2 * b + 1];
    __shared__ short Al[64][40];
    __shared__ short Bl[128][40];
    int m0 = blockIdx.y * 64, n0 = blockIdx.x * 128;
    int tid = threadIdx.x;
    int wave = tid >> 6, lane = tid & 63, quad = lane >> 4, l16 = lane & 15;
    int wn = wave * 32;
    float4v zero4 = {0.f, 0.f, 0.f, 0.f};
    float4v acc[4][2];
    #pragma unroll
    for (int i = 0; i < 4; ++i)
        #pragma unroll
        for (int j = 0; j < 2; ++j) acc[i][j] = zero4;

    int am = tid >> 2, ako = (tid & 3) * 8;
    const short* HsA = Hs + (size_t)(2 * b) * NN * DHID;
    for (int kc = 0; kc < 32; ++kc) {
        int slot = kc >> 4;
        int kk = (kc & 15) * 32;
        const short* We = W2t_l + (size_t)(slot ? e1 : e0) * LL * DHID;
        {   // A: 64x32 from Hs (bf16)
            int gm = m0 + am;
            uint4 val = make_uint4(0, 0, 0, 0);
            if (gm < NN) val = *(const uint4*)(HsA + ((size_t)slot * NN + gm) * DHID + kk + ako);
            *(uint4*)&Al[am][ako] = val;
        }
        #pragma unroll
        for (int uu = 0; uu < 2; ++uu) {    // B: 128x32 from W2t [l][k]
            int u = tid + uu * 256;
            int n = u >> 2, ko = (u & 3) * 8;
            int gl = n0 + n;
            uint4 val = make_uint4(0, 0, 0, 0);
            if (gl < LL) val = *(const uint4*)(We + (size_t)gl * DHID + kk + ko);
            *(uint4*)&Bl[n][ko] = val;
        }
        __syncthreads();
        short8 af[4], bfv[2];
        #pragma unroll
        for (int mi = 0; mi < 4; ++mi) af[mi] = *(const short8*)&Al[mi * 16 + l16][quad * 8];
        #pragma unroll
        for (int ni = 0; ni < 2; ++ni) bfv[ni] = *(const short8*)&Bl[wn + ni * 16 + l16][quad * 8];
        #pragma unroll
        for (int mi = 0; mi < 4; ++mi)
            #pragma unroll
            for (int ni = 0; ni < 2; ++ni)
                acc[mi][ni] = __builtin_amdgcn_mfma_f32_16x16x32_bf16(af[mi], bfv[ni], acc[mi][ni], 0, 0, 0);
        __syncthreads();
    }
    const float* b2e0 = b2_l + (size_t)e0 * LL;
    const float* b2e1 = b2_l + (size_t)e1 * LL;
    float bias[2]; int glc[2];
    #pragma unroll
    for (int ni = 0; ni < 2; ++ni) {
        int gl = n0 + wn + ni * 16 + l16;
        glc[ni] = gl;
        bias[ni] = (gl < LL) ? (g0 * b2e0[gl] + g1 * b2e1[gl]) : 0.f;
    }
    float* Tb = T + (size_t)b * NN * LL;
    #pragma unroll
    for (int mi = 0; mi < 4; ++mi) {
        #pragma unroll
        for (int r = 0; r < 4; ++r) {
            int gm = m0 + mi * 16 + quad * 4 + r;
            if (gm >= NN) continue;
            #pragma unroll
            for (int ni = 0; ni < 2; ++ni) {
                if (glc[ni] < LL)
                    Tb[(size_t)gm * LL + glc[ni]] += acc[mi][ni][r] + bias[ni];
            }
        }
    }
}

// ---------------- fused projection head (MFMA), transposed phase 2 ----------------
// grid 161, 256 thr. Phase1: Hp(LDS) = tanh(T@p1w^T + p1b) for 64 m-rows.
// Phase2 (transposed): D[c][node] = p2w @ Hp^T + p2b -> coalesced-ish stores.
__global__ __launch_bounds__(256) void proj_fused(
    const float* __restrict__ T,
    const short* __restrict__ p1wb, const float* __restrict__ p1b,
    const short* __restrict__ p2wb, const float* __restrict__ p2b,
    float* __restrict__ out)
{
    __shared__ short smem[26624];                       // 52 KB, manually carved
    short (*Al)[40]   = (short (*)[40])smem;            // 64x40   (phase 1)
    short (*Bl1)[40]  = (short (*)[40])(smem + 2560);   // 96x40   (phase 1)
    short (*B2)[104]  = (short (*)[104])smem;           // 192x104 (phase 2, overlays Al/Bl1)
    short (*Hp)[104]  = (short (*)[104])(smem + 19968); // 64x104

    int m0 = blockIdx.x * 64;
    int tid = threadIdx.x;
    int wave = tid >> 6, lane = tid & 63, quad = lane >> 4, l16 = lane & 15;
    float4v zero4 = {0.f, 0.f, 0.f, 0.f};

    // ---- phase 1: 64 x 96 = T-tile @ p1w^T ----
    float4v acc1[6];
    #pragma unroll
    for (int i = 0; i < 6; ++i) acc1[i] = zero4;
    int am = tid >> 2, ako = (tid & 3) * 8;
    for (int k0 = 0; k0 < LL; k0 += 32) {
        {
            int gm = m0 + am, gk = k0 + ako;
            S8 s;
            if (gm < MROWS && gk < LL) {
                const float* p = T + (size_t)gm * LL + gk;
                #pragma unroll
                for (int j = 0; j < 8; ++j) s.s[j] = f2b(p[j]);
            } else {
                s.u = make_uint4(0, 0, 0, 0);
            }
            *(uint4*)&Al[am][ako] = s.u;
        }
        #pragma unroll
        for (int uu = 0; uu < 2; ++uu) {
            int u = tid + uu * 256;
            if (u < 384) {
                int n = u >> 2, ko = (u & 3) * 8;
                int gk = k0 + ko;
                uint4 val = make_uint4(0, 0, 0, 0);
                if (gk < LL) val = *(const uint4*)(p1wb + (size_t)n * LL + gk);
                *(uint4*)&Bl1[n][ko] = val;
            }
        }
        __syncthreads();
        short8 af = *(const short8*)&Al[wave * 16 + l16][quad * 8];
        #pragma unroll
        for (int ni = 0; ni < 6; ++ni) {
            short8 bfv = *(const short8*)&Bl1[ni * 16 + l16][quad * 8];
            acc1[ni] = __builtin_amdgcn_mfma_f32_16x16x32_bf16(af, bfv, acc1[ni], 0, 0, 0);
        }
        __syncthreads();   // also protects Al/Bl1 before B2 overlay
    }
    // write Hp tile (LDS) + stage p2w fully into B2 (overlays Al/Bl1 — safe after sync)
    #pragma unroll
    for (int ni = 0; ni < 6; ++ni) {
        #pragma unroll
        for (int r = 0; r < 4; ++r) {
            int ml = wave * 16 + quad * 4 + r;
            int p = ni * 16 + l16;
            Hp[ml][p] = f2b(fast_tanh(acc1[ni][r] + p1b[p]));
        }
    }
    for (int u = tid; u < 192 * 12; u += 256) {
        int n = u / 12, ko = (u - n * 12) * 8;
        *(uint4*)&B2[n][ko] = *(const uint4*)(p2wb + (size_t)n * PP + ko);
    }
    __syncthreads();

    // ---- phase 2 (transposed): rows = c (192), cols = node (64), K = 96 ----
    float4v acc2[3][4];
    #pragma unroll
    for (int i = 0; i < 3; ++i)
        #pragma unroll
        for (int j = 0; j < 4; ++j) acc2[i][j] = zero4;
    #pragma unroll
    for (int kc = 0; kc < 3; ++kc) {
        int k0 = kc * 32 + quad * 8;
        short8 af[3], bfv[4];
        #pragma unroll
        for (int mi = 0; mi < 3; ++mi) af[mi] = *(const short8*)&B2[wave * 48 + mi * 16 + l16][k0];
        #pragma unroll
        for (int ni = 0; ni < 4; ++ni) bfv[ni] = *(const short8*)&Hp[ni * 16 + l16][k0];
        #pragma unroll
        for (int mi = 0; mi < 3; ++mi)
            #pragma unroll
            for (int ni = 0; ni < 4; ++ni)
                acc2[mi][ni] = __builtin_amdgcn_mfma_f32_16x16x32_bf16(af[mi], bfv[ni], acc2[mi][ni], 0, 0, 0);
    }
    // stores: lane l16 -> consecutive node (coalesced 64B runs per quad)
    int bqv[4], ndv[4]; bool okv[4];
    #pragma unroll
    for (int ni = 0; ni < 4; ++ni) {
        int gm = m0 + ni * 16 + l16;
        okv[ni] = (gm < MROWS);
        int bq = gm / NN;
        bqv[ni] = bq; ndv[ni] = gm - bq * NN;
    }
    #pragma unroll
    for (int mi = 0; mi < 3; ++mi) {
        #pragma unroll
        for (int r = 0; r < 4; ++r) {
            int c = wave * 48 + mi * 16 + quad * 4 + r;
            float pb = p2b[c];
            int p = c >> 1;
            if ((r & 1) == 0) {               // c even -> mean
                #pragma unroll
                for (int ni = 0; ni < 4; ++ni) {
                    if (!okv[ni]) continue;
                    float v = acc2[mi][ni][r] + pb;
                    out[((size_t)bqv[ni] * PP + p) * NN + ndv[ni]] = v;
                }
            } else {                          // c odd -> std
                #pragma unroll
                for (int ni = 0; ni < 4; ++ni) {
                    if (!okv[ni]) continue;
                    float v = acc2[mi][ni][r] + pb;
                    out[BPN + 1 + ((size_t)bqv[ni] * PP + p) * NN + ndv[ni]] = softplus_f(v) + 1e-6f;
                }
            }
        }
    }
}

__global__ void loss_write_kernel(const float* __restrict__ loss, float* __restrict__ out)
{
    if (threadIdx.x == 0) out[BPN] = loss[0];
}

extern "C" void kernel_launch(void* const* d_in, const int* in_sizes, int n_in,
                              void* d_out, int out_size, void* d_ws, size_t ws_size,
                              hipStream_t stream)
{
    const float* x     = (const float*)d_in[0];
    const float* noise = (const float*)d_in[1];
    const float* wg    = (const float*)d_in[2];
    const float* wn    = (const float*)d_in[3];
    const float* W1    = (const float*)d_in[4];
    const float* b1    = (const float*)d_in[5];
    const float* W2    = (const float*)d_in[6];
    const float* b2    = (const float*)d_in[7];
    const float* p1w   = (const float*)d_in[8];
    const float* p1b   = (const float*)d_in[9];
    const float* p2w   = (const float*)d_in[10];
    const float* p2b   = (const float*)d_in[11];
    float* out = (float*)d_out;

    float* ws   = (float*)d_ws;
    float* T    = ws;                          // STOT fp32
    float* G    = T + STOT;                    // BB*LL
    float* G8   = G + BB * LL;                 // 8*BB*LL
    float* LOSS = G8 + 8 * BB * LL;            // 8
    float* GV   = LOSS + 8;                    // 64
    int*   IDX  = (int*)(GV + 64);             // 64
    short* W1t  = (short*)(IDX + 64);          // NW1 bf16 [le][d][k]
    short* W2t  = W1t + NW1;                   // NW1 bf16 [le][d][k]
    short* p1wb = W2t + NW1;                   // 96*336
    short* p2wb = p1wb + PP * LL;              // 192*96
    short* Hs   = p2wb + 2 * PP * PP;          // 64*321*512 bf16

    revin_kernel<<<(MROWS + 255) / 256, 256, 0, stream>>>(x, T, LOSS);

    int wtot = 2 * NW1 + PP * LL + 2 * PP * PP;
    wcvt_kernel<<<(wtot + 255) / 256, 256, 0, stream>>>(W1, W2, p1w, p2w, W1t, W2t, p1wb, p2wb);

    for (int l = 0; l < NLAYERS; ++l) {
        gmean_part<<<dim3(BB, 8), 384, 0, stream>>>(T, G8);
        gmean_red<<<BB, 384, 0, stream>>>(G8, G);
        gating_kernel<<<1, 128, 0, stream>>>(G, wg + (size_t)l * LL * EE, wn + (size_t)l * LL * EE,
                                             noise + (size_t)l * BB * EE, IDX, GV, LOSS);
        fc1_mfma<<<dim3(4, 6, 64), 256, 0, stream>>>(
            T, W1t + (size_t)l * EE * DHID * LL, b1 + (size_t)l * EE * DHID, IDX, GV, Hs);
        fc2_mfma<<<dim3(3, 6, 32), 256, 0, stream>>>(
            Hs, W2t + (size_t)l * EE * LL * DHID, b2 + (size_t)l * EE * LL, T, IDX, GV);
    }
    proj_fused<<<161, 256, 0, stream>>>(T, p1wb, p1b, p2wb, p2b, out);
    loss_write_kernel<<<1, 64, 0, stream>>>(LOSS, out);
}